// Round 3
// baseline (107.220 us; speedup 1.0000x reference)
//
#include <hip/hip_runtime.h>
#include <math.h>

#define BB 16
#define TT 24
#define NN 128
#define DD 64
#define PTOT (BB * TT * NN)   // 49152 positions
#define P64  (PTOT * 64)      // elements per (B,T,N,64) buffer

typedef __attribute__((ext_vector_type(8))) short bf16x8;
typedef __attribute__((ext_vector_type(4))) float f32x4;

__device__ __forceinline__ unsigned short f2bf(float f) {
    unsigned u = __builtin_bit_cast(unsigned, f);
    u = (u + 0x7fffu + ((u >> 16) & 1u)) >> 16;   // round-to-nearest-even
    return (unsigned short)u;
}
__device__ __forceinline__ void unpack8(uint4 u, float* f) {
    f[0] = __builtin_bit_cast(float, u.x << 16);
    f[1] = __builtin_bit_cast(float, u.x & 0xFFFF0000u);
    f[2] = __builtin_bit_cast(float, u.y << 16);
    f[3] = __builtin_bit_cast(float, u.y & 0xFFFF0000u);
    f[4] = __builtin_bit_cast(float, u.z << 16);
    f[5] = __builtin_bit_cast(float, u.z & 0xFFFF0000u);
    f[6] = __builtin_bit_cast(float, u.w << 16);
    f[7] = __builtin_bit_cast(float, u.w & 0xFFFF0000u);
}
__device__ __forceinline__ uint4 pack8(const float* f) {
    uint4 o;
    o.x = (unsigned)f2bf(f[0]) | ((unsigned)f2bf(f[1]) << 16);
    o.y = (unsigned)f2bf(f[2]) | ((unsigned)f2bf(f[3]) << 16);
    o.z = (unsigned)f2bf(f[4]) | ((unsigned)f2bf(f[5]) << 16);
    o.w = (unsigned)f2bf(f[6]) | ((unsigned)f2bf(f[7]) << 16);
    return o;
}
__device__ __forceinline__ float fast_exp2(float x) {
#if __has_builtin(__builtin_amdgcn_exp2f)
    return __builtin_amdgcn_exp2f(x);
#else
    return exp2f(x);
#endif
}

// ---------------------------------------------------------------------------
// Kernel 0: combined weight prep.
// blocks 0..287: 6 proj weights (192x64) -> bf16 [j][n][k]  (Wt)
// blocks 288..415: 8 epi weights (64x64) -> bf16 [mat][n][k] (Wt8)
// ---------------------------------------------------------------------------
__global__ __launch_bounds__(256) void wprep_all(
    const float* __restrict__ W0, const float* __restrict__ W1,
    const float* __restrict__ W2, const float* __restrict__ W3,
    const float* __restrict__ W4, const float* __restrict__ W5,
    const float* __restrict__ E0, const float* __restrict__ E1,
    const float* __restrict__ E2, const float* __restrict__ E3,
    const float* __restrict__ E4, const float* __restrict__ E5,
    const float* __restrict__ E6, const float* __restrict__ E7,
    unsigned short* __restrict__ Wt, unsigned short* __restrict__ Wt8)
{
    const int bid = blockIdx.x;
    if (bid < 288) {
        const float* Ws[6] = {W0, W1, W2, W3, W4, W5};
        const int e = bid * 256 + threadIdx.x;          // < 73728
        const int j = e / 12288;
        const int r = e % 12288;
        const int k = r / 64;
        const int n = r % 64;
        Wt[j * 12288 + n * 192 + k] = f2bf(Ws[j][k * 64 + n]);
    } else {
        const float* Es[8] = {E0, E1, E2, E3, E4, E5, E6, E7};
        const int e = (bid - 288) * 256 + threadIdx.x;  // < 32768
        const int mat = e >> 12;
        const int r = e & 4095;
        const int k = r >> 6;
        const int n = r & 63;
        Wt8[mat * 4096 + n * 64 + k] = f2bf(Es[mat][k * 64 + n]);
    }
}

// ---------------------------------------------------------------------------
// Kernel 1: 6-way QKV projection (GEMM only, attention split out).
// Grid = PTOT/64 = 768 blocks x 256 thr (4 waves); each block does 64
// positions (4 mt iters of 16). Wave w owns channel tile w; 36 weight frags
// in VGPRs; XE staged 16 rows at a time (double-buffered bf16 LDS).
// Outputs (all bf16, relu'd):
//   qs, qt, kt, vt : pos-major [pos][64ch]
//   ks, vs         : head-major [h][pos][8]  (coalesced sattn staging)
// LDS: only 12.8 KB now.
// ---------------------------------------------------------------------------
__global__ __launch_bounds__(256, 2) void proj_kernel(
    const float* __restrict__ X, const float* __restrict__ TLE,
    const unsigned short* __restrict__ Wt,   // [6][64][192] bf16
    const float* __restrict__ b0, const float* __restrict__ b1,
    const float* __restrict__ b2, const float* __restrict__ b3,
    const float* __restrict__ b4, const float* __restrict__ b5,
    unsigned short* __restrict__ qs, unsigned short* __restrict__ ks,
    unsigned short* __restrict__ vs,
    unsigned short* __restrict__ qt, unsigned short* __restrict__ kt,
    unsigned short* __restrict__ vt)
{
    __shared__ __align__(16) unsigned short xe[2][16][200];   // staged XE tile
    const int tid = threadIdx.x;
    const long p0 = (long)blockIdx.x * 64;
    const int w = tid >> 6, l = tid & 63, quad = l >> 4, l16 = l & 15;

    // ---- stage one 16-row XE tile (fp32 -> bf16) ----
    auto stage = [&](int mt, int buf) {
        #pragma unroll
        for (int i = 0; i < 3; ++i) {
            const int idx4 = tid + i * 256;     // < 768 (16 rows * 48 float4)
            const int m  = idx4 / 48;
            const int kq = idx4 % 48;
            const int k  = kq * 4;
            const long p = p0 + mt * 16 + m;
            float4 v;
            if (k < 64) v = *reinterpret_cast<const float4*>(X + p * 64 + k);
            else        v = *reinterpret_cast<const float4*>(TLE + p * 128 + (k - 64));
            ushort4 pk;
            pk.x = f2bf(v.x); pk.y = f2bf(v.y); pk.z = f2bf(v.z); pk.w = f2bf(v.w);
            *reinterpret_cast<ushort4*>(&xe[buf][m][k]) = pk;
        }
    };

    // ---- preload all 36 weight fragments (ch rows = w*16 + l16) ----
    bf16x8 wf[6][6];
    #pragma unroll
    for (int mat = 0; mat < 6; ++mat)
        #pragma unroll
        for (int kc = 0; kc < 6; ++kc)
            wf[mat][kc] = *reinterpret_cast<const bf16x8*>(
                &Wt[mat * 12288 + (w * 16 + l16) * 192 + kc * 32 + quad * 8]);

    const float* bias_p[6] = {b0, b1, b2, b3, b4, b5};
    float4 bias[6];
    #pragma unroll
    for (int mat = 0; mat < 6; ++mat)
        bias[mat] = *reinterpret_cast<const float4*>(&bias_p[mat][w * 16 + quad * 4]);

    stage(0, 0);
    __syncthreads();

    const int chBase = w * 16 + quad * 4;         // channel base (pos-major)
    const int hh  = w * 2 + (quad >> 1);          // head (head-major layout)
    const int dd0 = (quad & 1) * 4;               // dim offset within head

    auto packrelu = [&](const f32x4& a, const float4& b) {
        ushort4 pk;
        pk.x = f2bf(fmaxf(a[0] + b.x, 0.f));
        pk.y = f2bf(fmaxf(a[1] + b.y, 0.f));
        pk.z = f2bf(fmaxf(a[2] + b.z, 0.f));
        pk.w = f2bf(fmaxf(a[3] + b.w, 0.f));
        return pk;
    };

    for (int mt = 0; mt < 4; ++mt) {
        if (mt < 3) stage(mt + 1, (mt + 1) & 1);

        bf16x8 A[6];
        #pragma unroll
        for (int kc = 0; kc < 6; ++kc)
            A[kc] = *reinterpret_cast<const bf16x8*>(
                &xe[mt & 1][l16][kc * 32 + quad * 8]);

        f32x4 acc[6];
        #pragma unroll
        for (int mat = 0; mat < 6; ++mat) acc[mat] = (f32x4){0.f, 0.f, 0.f, 0.f};
        #pragma unroll
        for (int kc = 0; kc < 6; ++kc)
            #pragma unroll
            for (int mat = 0; mat < 6; ++mat)
                acc[mat] = __builtin_amdgcn_mfma_f32_16x16x32_bf16(
                    wf[mat][kc], A[kc], acc[mat], 0, 0, 0);

        const int pos = mt * 16 + l16;            // lane's position (C/D col)
        const long gp = (p0 + pos) * 64 + chBase;                 // pos-major
        const long gs = ((long)hh * PTOT + p0 + pos) * 8 + dd0;   // head-major

        *reinterpret_cast<ushort4*>(&qs[gp]) = packrelu(acc[0], bias[0]);
        *reinterpret_cast<ushort4*>(&ks[gs]) = packrelu(acc[1], bias[1]);
        *reinterpret_cast<ushort4*>(&vs[gs]) = packrelu(acc[2], bias[2]);
        *reinterpret_cast<ushort4*>(&qt[gp]) = packrelu(acc[3], bias[3]);
        *reinterpret_cast<ushort4*>(&kt[gp]) = packrelu(acc[4], bias[4]);
        *reinterpret_cast<ushort4*>(&vt[gp]) = packrelu(acc[5], bias[5]);
        __syncthreads();
    }
}

// ---------------------------------------------------------------------------
// Kernel 1b: spatial attention, one block per (b,t,head).
// Grid = BB*TT*8 = 3072 blocks x 128 threads (2 waves); thread = query row.
// K/V staged as f32 in LDS (8 KB) -> no per-iter unpack; loop reads are
// wave-uniform broadcasts (conflict-free). 1-deep software prefetch.
// Single-pass softmax w/o max (inputs relu'd, dots bounded), exp2-folded q.
// Whole grid co-resident (~12 blocks/CU, ~6 waves/SIMD).
// Writes HS over qs (same thread, same address -> alias-safe).
// ---------------------------------------------------------------------------
__global__ __launch_bounds__(128, 6) void sattn_kernel(
    const unsigned short* __restrict__ qs, const unsigned short* __restrict__ ks,
    const unsigned short* __restrict__ vs,
    unsigned short* __restrict__ HS)
{
    __shared__ __align__(16) float kk[NN][8];
    __shared__ __align__(16) float vv[NN][8];
    const int tid = threadIdx.x;          // query row 0..127
    const int h   = blockIdx.x & 7;       // head
    const long p0 = (long)(blockIdx.x >> 3) * 128;

    // ---- stage this head's K,V (head-major, coalesced 16B/lane) ----
    {
        const long hb = ((long)h * PTOT + p0) * 8;
        uint4 ku = *reinterpret_cast<const uint4*>(&ks[hb + tid * 8]);
        uint4 vu = *reinterpret_cast<const uint4*>(&vs[hb + tid * 8]);
        float kf[8], vf[8];
        unpack8(ku, kf); unpack8(vu, vf);
        #pragma unroll
        for (int d = 0; d < 8; ++d) { kk[tid][d] = kf[d]; vv[tid][d] = vf[d]; }
    }

    // ---- q for this thread's row (pos-major), pre-scaled by scale*log2e ----
    const float cs = 0.35355339059327373f * 1.4426950408889634f;
    float q[8];
    {
        uint4 qu = *reinterpret_cast<const uint4*>(&qs[(p0 + tid) * 64 + h * 8]);
        float qf[8]; unpack8(qu, qf);
        #pragma unroll
        for (int d = 0; d < 8; ++d) q[d] = qf[d] * cs;
    }
    __syncthreads();

    float sum = 0.f;
    float acc[8];
    #pragma unroll
    for (int d = 0; d < 8; ++d) acc[d] = 0.f;

    float4 ka = *reinterpret_cast<const float4*>(&kk[0][0]);
    float4 kb = *reinterpret_cast<const float4*>(&kk[0][4]);
    float4 va = *reinterpret_cast<const float4*>(&vv[0][0]);
    float4 vb = *reinterpret_cast<const float4*>(&vv[0][4]);
    for (int m = 0; m < NN; ++m) {
        const int mn = (m + 1) & (NN - 1);
        float4 kan = *reinterpret_cast<const float4*>(&kk[mn][0]);
        float4 kbn = *reinterpret_cast<const float4*>(&kk[mn][4]);
        float4 van = *reinterpret_cast<const float4*>(&vv[mn][0]);
        float4 vbn = *reinterpret_cast<const float4*>(&vv[mn][4]);

        float s = q[0] * ka.x;
        s = fmaf(q[1], ka.y, s); s = fmaf(q[2], ka.z, s); s = fmaf(q[3], ka.w, s);
        s = fmaf(q[4], kb.x, s); s = fmaf(q[5], kb.y, s); s = fmaf(q[6], kb.z, s);
        s = fmaf(q[7], kb.w, s);
        const float e = fast_exp2(s);
        sum += e;
        acc[0] = fmaf(e, va.x, acc[0]); acc[1] = fmaf(e, va.y, acc[1]);
        acc[2] = fmaf(e, va.z, acc[2]); acc[3] = fmaf(e, va.w, acc[3]);
        acc[4] = fmaf(e, vb.x, acc[4]); acc[5] = fmaf(e, vb.y, acc[5]);
        acc[6] = fmaf(e, vb.z, acc[6]); acc[7] = fmaf(e, vb.w, acc[7]);

        ka = kan; kb = kbn; va = van; vb = vbn;
    }

    const float inv = 1.0f / sum;
    float o[8];
    #pragma unroll
    for (int d = 0; d < 8; ++d) o[d] = acc[d] * inv;
    *reinterpret_cast<uint4*>(&HS[(p0 + tid) * 64 + h * 8]) = pack8(o);
}

// ---------------------------------------------------------------------------
// Kernel 2: temporal attention (causal + key padding), bf16 I/O.
// One block per (b, n); 192 threads = (head h, query time i).
// Writes O over Q (same thread, same address -> alias-safe).
// ---------------------------------------------------------------------------
__global__ __launch_bounds__(192) void tattn_kernel(
    const unsigned short* __restrict__ Q, const unsigned short* __restrict__ Kb,
    const unsigned short* __restrict__ V, const int* __restrict__ kpm,
    unsigned short* __restrict__ O)
{
    __shared__ float kk[8][TT][8];
    __shared__ float vv[8][TT][8];
    const int tid = threadIdx.x;
    const int n = blockIdx.x & (NN - 1);
    const int b = blockIdx.x >> 7;

    {   // staging: thread = (head hs, time j): one 16-B bf16 load each for K and V
        const int hs = tid / TT;
        const int j  = tid % TT;
        const long g = (((long)(b * TT + j)) * NN + n) * 64 + hs * 8;
        uint4 ku = *reinterpret_cast<const uint4*>(&Kb[g]);
        uint4 vu = *reinterpret_cast<const uint4*>(&V[g]);
        float kf[8], vf[8];
        unpack8(ku, kf); unpack8(vu, vf);
        #pragma unroll
        for (int d = 0; d < 8; ++d) { kk[hs][j][d] = kf[d]; vv[hs][j][d] = vf[d]; }
    }

    const int h = tid / TT;
    const int i = tid % TT;
    const long qb = (((long)(b * TT + i)) * NN + n) * 64 + h * 8;
    float q[8];
    {
        uint4 qu = *reinterpret_cast<const uint4*>(&Q[qb]);
        unpack8(qu, q);
    }
    __syncthreads();

    const int kp = kpm[b];
    const float scale = 0.35355339059327373f;

    float s[TT];
    #pragma unroll
    for (int j = 0; j < TT; ++j) {
        float t = 0.0f;
        #pragma unroll
        for (int d = 0; d < 8; ++d) t = fmaf(q[d], kk[h][j][d], t);
        s[j] = (j <= i && j < kp) ? t * scale : -INFINITY;
    }
    float mx = -INFINITY;
    #pragma unroll
    for (int j = 0; j < TT; ++j) mx = fmaxf(mx, s[j]);

    float sum = 0.0f;
    float acc[8];
    #pragma unroll
    for (int d = 0; d < 8; ++d) acc[d] = 0.0f;
    #pragma unroll
    for (int j = 0; j < TT; ++j) {
        const float e = __expf(s[j] - mx);  // masked -> exp(-inf)=0
        sum += e;
        #pragma unroll
        for (int d = 0; d < 8; ++d) acc[d] = fmaf(e, vv[h][j][d], acc[d]);
    }
    const float inv = 1.0f / sum;
    float o[8];
    #pragma unroll
    for (int d = 0; d < 8; ++d) o[d] = acc[d] * inv;
    *reinterpret_cast<uint4*>(&O[qb]) = pack8(o);
}

// ---------------------------------------------------------------------------
// Kernel 3: epilogue via bf16 MFMA, swapped operands.
// Block = 256 thr (4 waves), 64-position tile.  Grid = PTOT/64 = 768.
// HS/HT arrive as bf16 -> staging is a straight copy (no conversion).
// ---------------------------------------------------------------------------
__global__ __launch_bounds__(256) void epi_kernel(
    const float* __restrict__ X,
    const unsigned short* __restrict__ HSb, const unsigned short* __restrict__ HTb,
    const unsigned short* __restrict__ Wt8,  // [8][64][64] bf16
    const float* __restrict__ sbo1, const float* __restrict__ sbo2,
    const float* __restrict__ tbo1, const float* __restrict__ tbo2,
    const float* __restrict__ bxt,
    const float* __restrict__ bh1, const float* __restrict__ bh2,
    float* __restrict__ out)
{
    constexpr int RS = 72;
    __shared__ __align__(16) unsigned short bufA[64][RS], bufB[64][RS], bufC[64][RS];
    const int tid = threadIdx.x;
    const long p0 = (long)blockIdx.x * 64;
    const int w = tid >> 6, l = tid & 63, quad = l >> 4, l16 = l & 15;
    const int chBase = w * 16 + quad * 4;

    // ---- stage HS -> bufA, HT -> bufC (straight bf16 copy) ----
    #pragma unroll
    for (int i = 0; i < 4; ++i) {
        const int idx = tid + i * 256;      // < 1024
        const int m = idx >> 4;
        const int c = (idx & 15) * 4;
        *reinterpret_cast<ushort4*>(&bufA[m][c]) =
            *reinterpret_cast<const ushort4*>(&HSb[(p0 + m) * 64 + c]);
        *reinterpret_cast<ushort4*>(&bufC[m][c]) =
            *reinterpret_cast<const ushort4*>(&HTb[(p0 + m) * 64 + c]);
    }
    __syncthreads();

    auto gemm = [&](const unsigned short (*in)[RS], int mat,
                    const float* __restrict__ bias, f32x4* accO) {
        bf16x8 af[2];
        #pragma unroll
        for (int kc = 0; kc < 2; ++kc)
            af[kc] = *reinterpret_cast<const bf16x8*>(
                &Wt8[mat * 4096 + (w * 16 + l16) * 64 + kc * 32 + quad * 8]);
        const float4 b4 = *reinterpret_cast<const float4*>(&bias[chBase]);
        #pragma unroll
        for (int pt = 0; pt < 4; ++pt) {
            f32x4 acc = (f32x4){0.f, 0.f, 0.f, 0.f};
            #pragma unroll
            for (int kc = 0; kc < 2; ++kc) {
                bf16x8 bf = *reinterpret_cast<const bf16x8*>(
                    &in[pt * 16 + l16][kc * 32 + quad * 8]);
                acc = __builtin_amdgcn_mfma_f32_16x16x32_bf16(af[kc], bf, acc, 0, 0, 0);
            }
            acc[0] += b4.x; acc[1] += b4.y; acc[2] += b4.z; acc[3] += b4.w;
            accO[pt] = acc;
        }
    };

    auto writeBuf = [&](unsigned short (*dst)[RS], const f32x4* v, bool relu) {
        #pragma unroll
        for (int pt = 0; pt < 4; ++pt) {
            float a0 = v[pt][0], a1 = v[pt][1], a2 = v[pt][2], a3 = v[pt][3];
            if (relu) { a0 = fmaxf(a0, 0.f); a1 = fmaxf(a1, 0.f);
                        a2 = fmaxf(a2, 0.f); a3 = fmaxf(a3, 0.f); }
            ushort4 pk; pk.x = f2bf(a0); pk.y = f2bf(a1); pk.z = f2bf(a2); pk.w = f2bf(a3);
            *reinterpret_cast<ushort4*>(&dst[pt * 16 + l16][chBase]) = pk;
        }
    };

    f32x4 t[4], HSr[4], HTr[4];

    gemm(bufA, 0, sbo1, t);                 // HS1 = relu(HS@sWo1+b)
    __syncthreads();
    writeBuf(bufB, t, true);
    __syncthreads();

    gemm(bufB, 1, sbo2, HSr);               // HS2 (fp32 regs)
    __syncthreads();
    writeBuf(bufA, HSr, false);
    __syncthreads();

    gemm(bufC, 2, tbo1, t);                 // HT1 = relu(HT@tWo1+b)
    __syncthreads();
    writeBuf(bufB, t, true);
    __syncthreads();

    gemm(bufB, 3, tbo2, HTr);               // HT2 (fp32 regs)
    __syncthreads();
    writeBuf(bufC, HTr, false);
    __syncthreads();

    // ---- gate ----
    {
        bf16x8 afS[2], afT[2];
        #pragma unroll
        for (int kc = 0; kc < 2; ++kc) {
            afS[kc] = *reinterpret_cast<const bf16x8*>(
                &Wt8[4 * 4096 + (w * 16 + l16) * 64 + kc * 32 + quad * 8]);
            afT[kc] = *reinterpret_cast<const bf16x8*>(
                &Wt8[5 * 4096 + (w * 16 + l16) * 64 + kc * 32 + quad * 8]);
        }
        const float4 b4 = *reinterpret_cast<const float4*>(&bxt[chBase]);
        #pragma unroll
        for (int pt = 0; pt < 4; ++pt) {
            f32x4 acc = (f32x4){0.f, 0.f, 0.f, 0.f};
            #pragma unroll
            for (int kc = 0; kc < 2; ++kc) {
                bf16x8 hsf = *reinterpret_cast<const bf16x8*>(
                    &bufA[pt * 16 + l16][kc * 32 + quad * 8]);
                acc = __builtin_amdgcn_mfma_f32_16x16x32_bf16(afS[kc], hsf, acc, 0, 0, 0);
            }
            #pragma unroll
            for (int kc = 0; kc < 2; ++kc) {
                bf16x8 htf = *reinterpret_cast<const bf16x8*>(
                    &bufC[pt * 16 + l16][kc * 32 + quad * 8]);
                acc = __builtin_amdgcn_mfma_f32_16x16x32_bf16(afT[kc], htf, acc, 0, 0, 0);
            }
            const float zb[4] = {acc[0] + b4.x, acc[1] + b4.y, acc[2] + b4.z, acc[3] + b4.w};
            f32x4 h;
            #pragma unroll
            for (int r = 0; r < 4; ++r) {
                const float z = 1.0f / (1.0f + __expf(-zb[r]));
                h[r] = z * HSr[pt][r] + (1.0f - z) * HTr[pt][r];
            }
            t[pt] = h;
        }
    }
    __syncthreads();
    writeBuf(bufB, t, false);
    __syncthreads();

    gemm(bufB, 6, bh1, t);                  // H1 = relu(H@Wh1+b)
    __syncthreads();
    writeBuf(bufA, t, true);
    __syncthreads();

    gemm(bufA, 7, bh2, t);                  // out = X + H1@Wh2+b
    #pragma unroll
    for (int pt = 0; pt < 4; ++pt) {
        const long pos = p0 + pt * 16 + l16;
        const float4 xv = *reinterpret_cast<const float4*>(&X[pos * 64 + chBase]);
        float4 o;
        o.x = t[pt][0] + xv.x; o.y = t[pt][1] + xv.y;
        o.z = t[pt][2] + xv.z; o.w = t[pt][3] + xv.w;
        *reinterpret_cast<float4*>(&out[pos * 64 + chBase]) = o;
    }
}

// ---------------------------------------------------------------------------
extern "C" void kernel_launch(void* const* d_in, const int* in_sizes, int n_in,
                              void* d_out, int out_size, void* d_ws, size_t ws_size,
                              hipStream_t stream) {
    const float* X   = (const float*)d_in[0];
    const float* TLE = (const float*)d_in[1];
    const int* kpm   = (const int*)d_in[2];

    const float* sa_Wq = (const float*)d_in[3];  const float* sa_bq = (const float*)d_in[4];
    const float* sa_Wk = (const float*)d_in[5];  const float* sa_bk = (const float*)d_in[6];
    const float* sa_Wv = (const float*)d_in[7];  const float* sa_bv = (const float*)d_in[8];
    const float* sa_Wo1 = (const float*)d_in[9];  const float* sa_bo1 = (const float*)d_in[10];
    const float* sa_Wo2 = (const float*)d_in[11]; const float* sa_bo2 = (const float*)d_in[12];
    const float* ta_Wq = (const float*)d_in[13]; const float* ta_bq = (const float*)d_in[14];
    const float* ta_Wk = (const float*)d_in[15]; const float* ta_bk = (const float*)d_in[16];
    const float* ta_Wv = (const float*)d_in[17]; const float* ta_bv = (const float*)d_in[18];
    const float* ta_Wo1 = (const float*)d_in[19]; const float* ta_bo1 = (const float*)d_in[20];
    const float* ta_Wo2 = (const float*)d_in[21]; const float* ta_bo2 = (const float*)d_in[22];
    const float* g_Wxs = (const float*)d_in[23];
    const float* g_Wxt = (const float*)d_in[24]; const float* g_bxt = (const float*)d_in[25];
    const float* g_Wh1 = (const float*)d_in[26]; const float* g_bh1 = (const float*)d_in[27];
    const float* g_Wh2 = (const float*)d_in[28]; const float* g_bh2 = (const float*)d_in[29];

    unsigned short* wsp = (unsigned short*)d_ws;
    unsigned short* qt  = wsp + 0L * P64;            // aliased: HTb (tattn in-place)
    unsigned short* kt  = wsp + 1L * P64;
    unsigned short* vt  = wsp + 2L * P64;
    unsigned short* qs  = wsp + 3L * P64;            // aliased: HSb (sattn in-place)
    unsigned short* ks  = wsp + 4L * P64;            // head-major [h][pos][8]
    unsigned short* vs  = wsp + 5L * P64;            // head-major [h][pos][8]
    unsigned short* Wt  = wsp + 6L * P64;            // 6*64*192 bf16
    unsigned short* Wt8 = Wt + 6 * 12288;            // 8*64*64 bf16
    unsigned short* HSb = qs;
    unsigned short* HTb = qt;

    float* out = (float*)d_out;

    hipLaunchKernelGGL(wprep_all, dim3(416), dim3(256), 0, stream,
                       sa_Wq, sa_Wk, sa_Wv, ta_Wq, ta_Wk, ta_Wv,
                       sa_Wo1, sa_Wo2, ta_Wo1, ta_Wo2, g_Wxs, g_Wxt, g_Wh1, g_Wh2,
                       Wt, Wt8);

    hipLaunchKernelGGL(proj_kernel, dim3(PTOT / 64), dim3(256), 0, stream,
                       X, TLE, Wt,
                       sa_bq, sa_bk, sa_bv, ta_bq, ta_bk, ta_bv,
                       qs, ks, vs, qt, kt, vt);

    hipLaunchKernelGGL(sattn_kernel, dim3(BB * TT * 8), dim3(128), 0, stream,
                       qs, ks, vs, HSb);

    hipLaunchKernelGGL(tattn_kernel, dim3(BB * NN), dim3(192), 0, stream,
                       qt, kt, vt, kpm, HTb);

    hipLaunchKernelGGL(epi_kernel, dim3(PTOT / 64), dim3(256), 0, stream,
                       X, HSb, HTb, Wt8,
                       sa_bo1, sa_bo2, ta_bo1, ta_bo2, g_bxt, g_bh1, g_bh2,
                       out);
}

// Round 4
// 82.418 us; speedup vs baseline: 1.3009x; 1.3009x over previous
//
#include <hip/hip_runtime.h>
#include <math.h>

#define BB 16
#define TT 24
#define NN 128
#define DD 64
#define PTOT (BB * TT * NN)   // 49152 positions
#define P64  (PTOT * 64)      // elements per (B,T,N,64) buffer

typedef __attribute__((ext_vector_type(8))) short bf16x8;
typedef __attribute__((ext_vector_type(4))) float f32x4;
typedef __attribute__((ext_vector_type(16))) float f32x16;

__device__ __forceinline__ unsigned short f2bf(float f) {
    unsigned u = __builtin_bit_cast(unsigned, f);
    u = (u + 0x7fffu + ((u >> 16) & 1u)) >> 16;   // round-to-nearest-even
    return (unsigned short)u;
}
__device__ __forceinline__ void unpack8(uint4 u, float* f) {
    f[0] = __builtin_bit_cast(float, u.x << 16);
    f[1] = __builtin_bit_cast(float, u.x & 0xFFFF0000u);
    f[2] = __builtin_bit_cast(float, u.y << 16);
    f[3] = __builtin_bit_cast(float, u.y & 0xFFFF0000u);
    f[4] = __builtin_bit_cast(float, u.z << 16);
    f[5] = __builtin_bit_cast(float, u.z & 0xFFFF0000u);
    f[6] = __builtin_bit_cast(float, u.w << 16);
    f[7] = __builtin_bit_cast(float, u.w & 0xFFFF0000u);
}
__device__ __forceinline__ uint4 pack8(const float* f) {
    uint4 o;
    o.x = (unsigned)f2bf(f[0]) | ((unsigned)f2bf(f[1]) << 16);
    o.y = (unsigned)f2bf(f[2]) | ((unsigned)f2bf(f[3]) << 16);
    o.z = (unsigned)f2bf(f[4]) | ((unsigned)f2bf(f[5]) << 16);
    o.w = (unsigned)f2bf(f[6]) | ((unsigned)f2bf(f[7]) << 16);
    return o;
}
__device__ __forceinline__ float fast_exp2(float x) {
#if __has_builtin(__builtin_amdgcn_exp2f)
    return __builtin_amdgcn_exp2f(x);
#else
    return exp2f(x);
#endif
}
__device__ __forceinline__ unsigned cvt_pk_bf16(float a, float b) {
    unsigned r;
    asm("v_cvt_pk_bf16_f32 %0, %1, %2" : "=v"(r) : "v"(a), "v"(b));
    return r;   // low16 = bf16(a), high16 = bf16(b)
}
__device__ __forceinline__ f32x16 zero16() {
    f32x16 z;
    #pragma unroll
    for (int i = 0; i < 16; ++i) z[i] = 0.f;
    return z;
}

// ---------------------------------------------------------------------------
// Kernel 0: combined weight prep.
// blocks 0..287: 6 proj weights (192x64) -> bf16 [j][n][k]  (Wt)
// blocks 288..415: 8 epi weights (64x64) -> bf16 [mat][n][k] (Wt8)
// ---------------------------------------------------------------------------
__global__ __launch_bounds__(256) void wprep_all(
    const float* __restrict__ W0, const float* __restrict__ W1,
    const float* __restrict__ W2, const float* __restrict__ W3,
    const float* __restrict__ W4, const float* __restrict__ W5,
    const float* __restrict__ E0, const float* __restrict__ E1,
    const float* __restrict__ E2, const float* __restrict__ E3,
    const float* __restrict__ E4, const float* __restrict__ E5,
    const float* __restrict__ E6, const float* __restrict__ E7,
    unsigned short* __restrict__ Wt, unsigned short* __restrict__ Wt8)
{
    const int bid = blockIdx.x;
    if (bid < 288) {
        const float* Ws[6] = {W0, W1, W2, W3, W4, W5};
        const int e = bid * 256 + threadIdx.x;          // < 73728
        const int j = e / 12288;
        const int r = e % 12288;
        const int k = r / 64;
        const int n = r % 64;
        Wt[j * 12288 + n * 192 + k] = f2bf(Ws[j][k * 64 + n]);
    } else {
        const float* Es[8] = {E0, E1, E2, E3, E4, E5, E6, E7};
        const int e = (bid - 288) * 256 + threadIdx.x;  // < 32768
        const int mat = e >> 12;
        const int r = e & 4095;
        const int k = r >> 6;
        const int n = r & 63;
        Wt8[mat * 4096 + n * 64 + k] = f2bf(Es[mat][k * 64 + n]);
    }
}

// ---------------------------------------------------------------------------
// Kernel 1: FUSED 6-way QKV projection + MFMA spatial attention.
// One block per (b,t): 128 positions, 256 threads (4 waves).
// GEMM phase: identical to the proven round-2 version (36 MFMAs/mt, XE
//   double-buffered, spatial q/k/v -> swizzled LDS, temporal -> global).
//   Spatial q is pre-scaled by softmax_scale*log2e at write.
// Attention phase (NEW, matrix-pipe): wave w handles heads {2w, 2w+1}.
//   Per (head, 32-query n-tile):
//     S^T tile = mfma_32x32x16(K_frag, Q_frag)  (d padded 8->16 w/ zeros)
//       C/D: lane holds col n = l&31, rows m = (reg&3)+8*(reg>>2)+4*(l>>5)
//       -> softmax denominator is lane-local: 64 adds + 1 shfl_xor(32).
//     exp2 in-register (no max subtraction; inputs relu'd, bounded).
//     P^T -> PV B-frags in-register: v_cvt_pk_bf16_f32 + 4 shfl_xor + selects.
//     O^T += mfma_32x32x16(V^T_frag, P^T_frag) over 8 m-chunks.
//   V^T frags: 64 exec-masked scalar LDS reads per head (no extra LDS).
// LDS: 2*16*200*2 + 3*128*64*2 = 61,952 B  (2 blocks/CU).
// ---------------------------------------------------------------------------
__global__ __launch_bounds__(256, 2) void fused_sattn(
    const float* __restrict__ X, const float* __restrict__ TLE,
    const unsigned short* __restrict__ Wt,   // [6][64][192] bf16
    const float* __restrict__ b0, const float* __restrict__ b1,
    const float* __restrict__ b2, const float* __restrict__ b3,
    const float* __restrict__ b4, const float* __restrict__ b5,
    unsigned short* __restrict__ qt, unsigned short* __restrict__ kt,
    unsigned short* __restrict__ vt,
    unsigned short* __restrict__ HS)
{
    __shared__ __align__(16) unsigned short xe[2][16][200];   // staged XE tile
    __shared__ __align__(16) unsigned short qq[128 * 64];     // swizzled bf16
    __shared__ __align__(16) unsigned short kk[128 * 64];
    __shared__ __align__(16) unsigned short vv[128 * 64];
    const int tid = threadIdx.x;
    const long p0 = (long)blockIdx.x * 128;
    const int w = tid >> 6, l = tid & 63, quad = l >> 4, l16 = l & 15;

    // ---- stage one 16-row XE tile (fp32 -> bf16) ----
    auto stage = [&](int mt, int buf) {
        #pragma unroll
        for (int i = 0; i < 3; ++i) {
            const int idx4 = tid + i * 256;     // < 768 (16 rows * 48 float4)
            const int m  = idx4 / 48;
            const int kq = idx4 % 48;
            const int k  = kq * 4;
            const long p = p0 + mt * 16 + m;
            float4 v;
            if (k < 64) v = *reinterpret_cast<const float4*>(X + p * 64 + k);
            else        v = *reinterpret_cast<const float4*>(TLE + p * 128 + (k - 64));
            ushort4 pk;
            pk.x = f2bf(v.x); pk.y = f2bf(v.y); pk.z = f2bf(v.z); pk.w = f2bf(v.w);
            *reinterpret_cast<ushort4*>(&xe[buf][m][k]) = pk;
        }
    };

    // ---- preload all 36 weight fragments (ch rows = w*16 + l16) ----
    bf16x8 wf[6][6];
    #pragma unroll
    for (int mat = 0; mat < 6; ++mat)
        #pragma unroll
        for (int kc = 0; kc < 6; ++kc)
            wf[mat][kc] = *reinterpret_cast<const bf16x8*>(
                &Wt[mat * 12288 + (w * 16 + l16) * 192 + kc * 32 + quad * 8]);

    const float* bias_p[6] = {b0, b1, b2, b3, b4, b5};
    float4 bias[6];
    #pragma unroll
    for (int mat = 0; mat < 6; ++mat)
        bias[mat] = *reinterpret_cast<const float4*>(&bias_p[mat][w * 16 + quad * 4]);

    stage(0, 0);
    __syncthreads();

    const int chunkW = ((w * 2 + (quad >> 1)));   // which 8-ch chunk this lane writes
    const int chSub  = (quad & 1) * 4;            // offset within chunk
    const int chBase = w * 16 + quad * 4;         // unswizzled channel base
    const float cs = 0.35355339059327373f * 1.4426950408889634f;  // scale*log2e

    for (int mt = 0; mt < 8; ++mt) {
        if (mt < 7) stage(mt + 1, (mt + 1) & 1);

        bf16x8 A[6];
        #pragma unroll
        for (int kc = 0; kc < 6; ++kc)
            A[kc] = *reinterpret_cast<const bf16x8*>(
                &xe[mt & 1][l16][kc * 32 + quad * 8]);

        f32x4 acc[6];
        #pragma unroll
        for (int mat = 0; mat < 6; ++mat) acc[mat] = (f32x4){0.f, 0.f, 0.f, 0.f};
        #pragma unroll
        for (int kc = 0; kc < 6; ++kc)
            #pragma unroll
            for (int mat = 0; mat < 6; ++mat)
                acc[mat] = __builtin_amdgcn_mfma_f32_16x16x32_bf16(
                    wf[mat][kc], A[kc], acc[mat], 0, 0, 0);

        const int pos = mt * 16 + l16;            // lane's position (C/D col)
        const int sw  = pos * 64 + ((chunkW ^ (pos & 7)) << 3) + chSub;  // LDS addr
        unsigned short* dstS[3] = {qq, kk, vv};
        #pragma unroll
        for (int mat = 0; mat < 3; ++mat) {       // spatial -> LDS (relu'd)
            const float sc = (mat == 0) ? cs : 1.0f;   // pre-scale q for exp2
            ushort4 pk;
            pk.x = f2bf(fmaxf(acc[mat][0] + bias[mat].x, 0.f) * sc);
            pk.y = f2bf(fmaxf(acc[mat][1] + bias[mat].y, 0.f) * sc);
            pk.z = f2bf(fmaxf(acc[mat][2] + bias[mat].z, 0.f) * sc);
            pk.w = f2bf(fmaxf(acc[mat][3] + bias[mat].w, 0.f) * sc);
            *reinterpret_cast<ushort4*>(&dstS[mat][sw]) = pk;
        }
        unsigned short* dstT[3] = {qt, kt, vt};
        const long gp = (p0 + pos) * 64 + chBase;
        #pragma unroll
        for (int m3 = 3; m3 < 6; ++m3) {          // temporal -> global bf16 (relu'd)
            ushort4 pk;
            pk.x = f2bf(fmaxf(acc[m3][0] + bias[m3].x, 0.f));
            pk.y = f2bf(fmaxf(acc[m3][1] + bias[m3].y, 0.f));
            pk.z = f2bf(fmaxf(acc[m3][2] + bias[m3].z, 0.f));
            pk.w = f2bf(fmaxf(acc[m3][3] + bias[m3].w, 0.f));
            *reinterpret_cast<ushort4*>(&dstT[m3 - 3][gp]) = pk;
        }
        __syncthreads();
    }

    // ---------------- MFMA attention phase ----------------
    const int hi = l >> 5;            // lane half (0/1)
    const int ln = l & 31;            // lane-in-half
    bf16x8 zf = {};

    // P^T-tile -> PV B-frag repack + 2 PV MFMAs (see header comment).
    auto pvstep = [&](f32x16& st, const bf16x8& va0, const bf16x8& va1,
                      f32x16& oacc) {
        const unsigned P0 = cvt_pk_bf16(st[0],  st[1]);
        const unsigned P1 = cvt_pk_bf16(st[2],  st[3]);
        const unsigned P2 = cvt_pk_bf16(st[4],  st[5]);
        const unsigned P3 = cvt_pk_bf16(st[6],  st[7]);
        const unsigned P4 = cvt_pk_bf16(st[8],  st[9]);
        const unsigned P5 = cvt_pk_bf16(st[10], st[11]);
        const unsigned P6 = cvt_pk_bf16(st[12], st[13]);
        const unsigned P7 = cvt_pk_bf16(st[14], st[15]);
        const unsigned V0 = __shfl_xor(hi ? P0 : P2, 32);
        const unsigned V1 = __shfl_xor(hi ? P1 : P3, 32);
        const unsigned V2 = __shfl_xor(hi ? P4 : P6, 32);
        const unsigned V3 = __shfl_xor(hi ? P5 : P7, 32);
        uint4 fe, fo;
        fe.x = hi ? V0 : P0; fe.y = hi ? V1 : P1;
        fe.z = hi ? P2 : V0; fe.w = hi ? P3 : V1;
        fo.x = hi ? V2 : P4; fo.y = hi ? V3 : P5;
        fo.z = hi ? P6 : V2; fo.w = hi ? P7 : V3;
        oacc = __builtin_amdgcn_mfma_f32_32x32x16_bf16(
            va0, __builtin_bit_cast(bf16x8, fe), oacc, 0, 0, 0);
        oacc = __builtin_amdgcn_mfma_f32_32x32x16_bf16(
            va1, __builtin_bit_cast(bf16x8, fo), oacc, 0, 0, 0);
    };

    #pragma unroll
    for (int hh2 = 0; hh2 < 2; ++hh2) {
        const int h = w * 2 + hh2;
        const int swz = (h ^ (ln & 7)) << 3;

        // K A-frags (4 m-tiles): lane ln holds K[row=mt*32+ln][d=hi*8+j];
        // hi=1 half is the d=8..15 zero padding.
        bf16x8 kf0 = hi ? zf : *reinterpret_cast<const bf16x8*>(&kk[(0 * 32 + ln) * 64 + swz]);
        bf16x8 kf1 = hi ? zf : *reinterpret_cast<const bf16x8*>(&kk[(1 * 32 + ln) * 64 + swz]);
        bf16x8 kf2 = hi ? zf : *reinterpret_cast<const bf16x8*>(&kk[(2 * 32 + ln) * 64 + swz]);
        bf16x8 kf3 = hi ? zf : *reinterpret_cast<const bf16x8*>(&kk[(3 * 32 + ln) * 64 + swz]);

        // V^T A-frags (8 m-chunks): lane ln<8 = dim d; rows d>=8 zero.
        bf16x8 vf[8];
        #pragma unroll
        for (int c = 0; c < 8; ++c) {
            bf16x8 f = zf;
            if (ln < 8) {
                #pragma unroll
                for (int j = 0; j < 8; ++j) {
                    const int m = c * 16 + hi * 8 + j;
                    f[j] = (short)vv[m * 64 + ((h ^ (m & 7)) << 3) + ln];
                }
            }
            vf[c] = f;
        }

        #pragma unroll
        for (int nt = 0; nt < 4; ++nt) {
            const int qrow = nt * 32 + ln;
            bf16x8 qf = hi ? zf : *reinterpret_cast<const bf16x8*>(&qq[qrow * 64 + swz]);

            f32x16 st0 = zero16(), st1 = zero16(), st2 = zero16(), st3 = zero16();
            st0 = __builtin_amdgcn_mfma_f32_32x32x16_bf16(kf0, qf, st0, 0, 0, 0);
            st1 = __builtin_amdgcn_mfma_f32_32x32x16_bf16(kf1, qf, st1, 0, 0, 0);
            st2 = __builtin_amdgcn_mfma_f32_32x32x16_bf16(kf2, qf, st2, 0, 0, 0);
            st3 = __builtin_amdgcn_mfma_f32_32x32x16_bf16(kf3, qf, st3, 0, 0, 0);

            float sum = 0.f;
            #pragma unroll
            for (int r = 0; r < 16; ++r) { st0[r] = fast_exp2(st0[r]); sum += st0[r]; }
            #pragma unroll
            for (int r = 0; r < 16; ++r) { st1[r] = fast_exp2(st1[r]); sum += st1[r]; }
            #pragma unroll
            for (int r = 0; r < 16; ++r) { st2[r] = fast_exp2(st2[r]); sum += st2[r]; }
            #pragma unroll
            for (int r = 0; r < 16; ++r) { st3[r] = fast_exp2(st3[r]); sum += st3[r]; }
            sum += __shfl_xor(sum, 32);

            f32x16 oacc = zero16();
            pvstep(st0, vf[0], vf[1], oacc);
            pvstep(st1, vf[2], vf[3], oacc);
            pvstep(st2, vf[4], vf[5], oacc);
            pvstep(st3, vf[6], vf[7], oacc);

            // O^T regs 0..3 hold d = 4*hi + reg for col n = qrow.
            const float inv = 1.0f / sum;
            ushort4 pk;
            pk.x = f2bf(oacc[0] * inv);
            pk.y = f2bf(oacc[1] * inv);
            pk.z = f2bf(oacc[2] * inv);
            pk.w = f2bf(oacc[3] * inv);
            *reinterpret_cast<ushort4*>(&HS[(p0 + qrow) * 64 + h * 8 + hi * 4]) = pk;
        }
    }
}

// ---------------------------------------------------------------------------
// Kernel 2: temporal attention (causal + key padding), bf16 I/O.
// One block per (b, n); 192 threads = (head h, query time i).
// ---------------------------------------------------------------------------
__global__ __launch_bounds__(192) void tattn_kernel(
    const unsigned short* __restrict__ Q, const unsigned short* __restrict__ Kb,
    const unsigned short* __restrict__ V, const int* __restrict__ kpm,
    unsigned short* __restrict__ O)
{
    __shared__ float kk[8][TT][8];
    __shared__ float vv[8][TT][8];
    const int tid = threadIdx.x;
    const int n = blockIdx.x & (NN - 1);
    const int b = blockIdx.x >> 7;

    {   // staging: thread = (head hs, time j): one 16-B bf16 load each for K and V
        const int hs = tid / TT;
        const int j  = tid % TT;
        const long g = (((long)(b * TT + j)) * NN + n) * 64 + hs * 8;
        uint4 ku = *reinterpret_cast<const uint4*>(&Kb[g]);
        uint4 vu = *reinterpret_cast<const uint4*>(&V[g]);
        float kf[8], vf[8];
        unpack8(ku, kf); unpack8(vu, vf);
        #pragma unroll
        for (int d = 0; d < 8; ++d) { kk[hs][j][d] = kf[d]; vv[hs][j][d] = vf[d]; }
    }

    const int h = tid / TT;
    const int i = tid % TT;
    const long qb = (((long)(b * TT + i)) * NN + n) * 64 + h * 8;
    float q[8];
    {
        uint4 qu = *reinterpret_cast<const uint4*>(&Q[qb]);
        unpack8(qu, q);
    }
    __syncthreads();

    const int kp = kpm[b];
    const float scale = 0.35355339059327373f;

    float s[TT];
    #pragma unroll
    for (int j = 0; j < TT; ++j) {
        float t = 0.0f;
        #pragma unroll
        for (int d = 0; d < 8; ++d) t = fmaf(q[d], kk[h][j][d], t);
        s[j] = (j <= i && j < kp) ? t * scale : -INFINITY;
    }
    float mx = -INFINITY;
    #pragma unroll
    for (int j = 0; j < TT; ++j) mx = fmaxf(mx, s[j]);

    float sum = 0.0f;
    float acc[8];
    #pragma unroll
    for (int d = 0; d < 8; ++d) acc[d] = 0.0f;
    #pragma unroll
    for (int j = 0; j < TT; ++j) {
        const float e = __expf(s[j] - mx);  // masked -> exp(-inf)=0
        sum += e;
        #pragma unroll
        for (int d = 0; d < 8; ++d) acc[d] = fmaf(e, vv[h][j][d], acc[d]);
    }
    const float inv = 1.0f / sum;
    float o[8];
    #pragma unroll
    for (int d = 0; d < 8; ++d) o[d] = acc[d] * inv;
    *reinterpret_cast<uint4*>(&O[qb]) = pack8(o);
}

// ---------------------------------------------------------------------------
// Kernel 3: epilogue via bf16 MFMA, swapped operands.
// Block = 256 thr (4 waves), 64-position tile.  Grid = PTOT/64 = 768.
// HS/HT arrive as bf16 -> staging is a straight copy (no conversion).
// ---------------------------------------------------------------------------
__global__ __launch_bounds__(256) void epi_kernel(
    const float* __restrict__ X,
    const unsigned short* __restrict__ HSb, const unsigned short* __restrict__ HTb,
    const unsigned short* __restrict__ Wt8,  // [8][64][64] bf16
    const float* __restrict__ sbo1, const float* __restrict__ sbo2,
    const float* __restrict__ tbo1, const float* __restrict__ tbo2,
    const float* __restrict__ bxt,
    const float* __restrict__ bh1, const float* __restrict__ bh2,
    float* __restrict__ out)
{
    constexpr int RS = 72;
    __shared__ __align__(16) unsigned short bufA[64][RS], bufB[64][RS], bufC[64][RS];
    const int tid = threadIdx.x;
    const long p0 = (long)blockIdx.x * 64;
    const int w = tid >> 6, l = tid & 63, quad = l >> 4, l16 = l & 15;
    const int chBase = w * 16 + quad * 4;

    // ---- stage HS -> bufA, HT -> bufC (straight bf16 copy) ----
    #pragma unroll
    for (int i = 0; i < 4; ++i) {
        const int idx = tid + i * 256;      // < 1024
        const int m = idx >> 4;
        const int c = (idx & 15) * 4;
        *reinterpret_cast<ushort4*>(&bufA[m][c]) =
            *reinterpret_cast<const ushort4*>(&HSb[(p0 + m) * 64 + c]);
        *reinterpret_cast<ushort4*>(&bufC[m][c]) =
            *reinterpret_cast<const ushort4*>(&HTb[(p0 + m) * 64 + c]);
    }
    __syncthreads();

    auto gemm = [&](const unsigned short (*in)[RS], int mat,
                    const float* __restrict__ bias, f32x4* accO) {
        bf16x8 af[2];
        #pragma unroll
        for (int kc = 0; kc < 2; ++kc)
            af[kc] = *reinterpret_cast<const bf16x8*>(
                &Wt8[mat * 4096 + (w * 16 + l16) * 64 + kc * 32 + quad * 8]);
        const float4 b4 = *reinterpret_cast<const float4*>(&bias[chBase]);
        #pragma unroll
        for (int pt = 0; pt < 4; ++pt) {
            f32x4 acc = (f32x4){0.f, 0.f, 0.f, 0.f};
            #pragma unroll
            for (int kc = 0; kc < 2; ++kc) {
                bf16x8 bf = *reinterpret_cast<const bf16x8*>(
                    &in[pt * 16 + l16][kc * 32 + quad * 8]);
                acc = __builtin_amdgcn_mfma_f32_16x16x32_bf16(af[kc], bf, acc, 0, 0, 0);
            }
            acc[0] += b4.x; acc[1] += b4.y; acc[2] += b4.z; acc[3] += b4.w;
            accO[pt] = acc;
        }
    };

    auto writeBuf = [&](unsigned short (*dst)[RS], const f32x4* v, bool relu) {
        #pragma unroll
        for (int pt = 0; pt < 4; ++pt) {
            float a0 = v[pt][0], a1 = v[pt][1], a2 = v[pt][2], a3 = v[pt][3];
            if (relu) { a0 = fmaxf(a0, 0.f); a1 = fmaxf(a1, 0.f);
                        a2 = fmaxf(a2, 0.f); a3 = fmaxf(a3, 0.f); }
            ushort4 pk; pk.x = f2bf(a0); pk.y = f2bf(a1); pk.z = f2bf(a2); pk.w = f2bf(a3);
            *reinterpret_cast<ushort4*>(&dst[pt * 16 + l16][chBase]) = pk;
        }
    };

    f32x4 t[4], HSr[4], HTr[4];

    gemm(bufA, 0, sbo1, t);                 // HS1 = relu(HS@sWo1+b)
    __syncthreads();
    writeBuf(bufB, t, true);
    __syncthreads();

    gemm(bufB, 1, sbo2, HSr);               // HS2 (fp32 regs)
    __syncthreads();
    writeBuf(bufA, HSr, false);
    __syncthreads();

    gemm(bufC, 2, tbo1, t);                 // HT1 = relu(HT@tWo1+b)
    __syncthreads();
    writeBuf(bufB, t, true);
    __syncthreads();

    gemm(bufB, 3, tbo2, HTr);               // HT2 (fp32 regs)
    __syncthreads();
    writeBuf(bufC, HTr, false);
    __syncthreads();

    // ---- gate ----
    {
        bf16x8 afS[2], afT[2];
        #pragma unroll
        for (int kc = 0; kc < 2; ++kc) {
            afS[kc] = *reinterpret_cast<const bf16x8*>(
                &Wt8[4 * 4096 + (w * 16 + l16) * 64 + kc * 32 + quad * 8]);
            afT[kc] = *reinterpret_cast<const bf16x8*>(
                &Wt8[5 * 4096 + (w * 16 + l16) * 64 + kc * 32 + quad * 8]);
        }
        const float4 b4 = *reinterpret_cast<const float4*>(&bxt[chBase]);
        #pragma unroll
        for (int pt = 0; pt < 4; ++pt) {
            f32x4 acc = (f32x4){0.f, 0.f, 0.f, 0.f};
            #pragma unroll
            for (int kc = 0; kc < 2; ++kc) {
                bf16x8 hsf = *reinterpret_cast<const bf16x8*>(
                    &bufA[pt * 16 + l16][kc * 32 + quad * 8]);
                acc = __builtin_amdgcn_mfma_f32_16x16x32_bf16(afS[kc], hsf, acc, 0, 0, 0);
            }
            #pragma unroll
            for (int kc = 0; kc < 2; ++kc) {
                bf16x8 htf = *reinterpret_cast<const bf16x8*>(
                    &bufC[pt * 16 + l16][kc * 32 + quad * 8]);
                acc = __builtin_amdgcn_mfma_f32_16x16x32_bf16(afT[kc], htf, acc, 0, 0, 0);
            }
            const float zb[4] = {acc[0] + b4.x, acc[1] + b4.y, acc[2] + b4.z, acc[3] + b4.w};
            f32x4 h;
            #pragma unroll
            for (int r = 0; r < 4; ++r) {
                const float z = 1.0f / (1.0f + __expf(-zb[r]));
                h[r] = z * HSr[pt][r] + (1.0f - z) * HTr[pt][r];
            }
            t[pt] = h;
        }
    }
    __syncthreads();
    writeBuf(bufB, t, false);
    __syncthreads();

    gemm(bufB, 6, bh1, t);                  // H1 = relu(H@Wh1+b)
    __syncthreads();
    writeBuf(bufA, t, true);
    __syncthreads();

    gemm(bufA, 7, bh2, t);                  // out = X + H1@Wh2+b
    #pragma unroll
    for (int pt = 0; pt < 4; ++pt) {
        const long pos = p0 + pt * 16 + l16;
        const float4 xv = *reinterpret_cast<const float4*>(&X[pos * 64 + chBase]);
        float4 o;
        o.x = t[pt][0] + xv.x; o.y = t[pt][1] + xv.y;
        o.z = t[pt][2] + xv.z; o.w = t[pt][3] + xv.w;
        *reinterpret_cast<float4*>(&out[pos * 64 + chBase]) = o;
    }
}

// ---------------------------------------------------------------------------
extern "C" void kernel_launch(void* const* d_in, const int* in_sizes, int n_in,
                              void* d_out, int out_size, void* d_ws, size_t ws_size,
                              hipStream_t stream) {
    const float* X   = (const float*)d_in[0];
    const float* TLE = (const float*)d_in[1];
    const int* kpm   = (const int*)d_in[2];

    const float* sa_Wq = (const float*)d_in[3];  const float* sa_bq = (const float*)d_in[4];
    const float* sa_Wk = (const float*)d_in[5];  const float* sa_bk = (const float*)d_in[6];
    const float* sa_Wv = (const float*)d_in[7];  const float* sa_bv = (const float*)d_in[8];
    const float* sa_Wo1 = (const float*)d_in[9];  const float* sa_bo1 = (const float*)d_in[10];
    const float* sa_Wo2 = (const float*)d_in[11]; const float* sa_bo2 = (const float*)d_in[12];
    const float* ta_Wq = (const float*)d_in[13]; const float* ta_bq = (const float*)d_in[14];
    const float* ta_Wk = (const float*)d_in[15]; const float* ta_bk = (const float*)d_in[16];
    const float* ta_Wv = (const float*)d_in[17]; const float* ta_bv = (const float*)d_in[18];
    const float* ta_Wo1 = (const float*)d_in[19]; const float* ta_bo1 = (const float*)d_in[20];
    const float* ta_Wo2 = (const float*)d_in[21]; const float* ta_bo2 = (const float*)d_in[22];
    const float* g_Wxs = (const float*)d_in[23];
    const float* g_Wxt = (const float*)d_in[24]; const float* g_bxt = (const float*)d_in[25];
    const float* g_Wh1 = (const float*)d_in[26]; const float* g_bh1 = (const float*)d_in[27];
    const float* g_Wh2 = (const float*)d_in[28]; const float* g_bh2 = (const float*)d_in[29];

    unsigned short* wsp = (unsigned short*)d_ws;
    unsigned short* qt  = wsp + 0L * P64;
    unsigned short* kt  = wsp + 1L * P64;
    unsigned short* vt  = wsp + 2L * P64;
    unsigned short* HSb = wsp + 3L * P64;
    unsigned short* HTb = wsp + 4L * P64;
    unsigned short* Wt  = wsp + 5L * P64;            // 6*64*192 bf16
    unsigned short* Wt8 = Wt + 6 * 12288;            // 8*64*64 bf16

    float* out = (float*)d_out;

    hipLaunchKernelGGL(wprep_all, dim3(416), dim3(256), 0, stream,
                       sa_Wq, sa_Wk, sa_Wv, ta_Wq, ta_Wk, ta_Wv,
                       sa_Wo1, sa_Wo2, ta_Wo1, ta_Wo2, g_Wxs, g_Wxt, g_Wh1, g_Wh2,
                       Wt, Wt8);

    hipLaunchKernelGGL(fused_sattn, dim3(BB * TT), dim3(256), 0, stream,
                       X, TLE, Wt,
                       sa_bq, sa_bk, sa_bv, ta_bq, ta_bk, ta_bv,
                       qt, kt, vt, HSb);

    hipLaunchKernelGGL(tattn_kernel, dim3(BB * NN), dim3(192), 0, stream,
                       qt, kt, vt, kpm, HTb);

    hipLaunchKernelGGL(epi_kernel, dim3(PTOT / 64), dim3(256), 0, stream,
                       X, HSb, HTb, Wt8,
                       sa_bo1, sa_bo2, ta_bo1, ta_bo2, g_bxt, g_bh1, g_bh2,
                       out);
}